// Round 11
// baseline (153.417 us; speedup 1.0000x reference)
//
#include <hip/hip_runtime.h>

#define NPTS   65536
#define DIM    128
#define KCODES 1024
#define BM     128      // points per argmin block
#define TILE_C 32       // codes per fragment-tile in ebf
#define NTHR   256      // 4 waves; each wave owns 32 points (ms = 0,1)
#define HALF_C 512      // codes per argmin block (codebook split in 2)

typedef short bf16x8 __attribute__((ext_vector_type(8)));
typedef float f32x4  __attribute__((ext_vector_type(4)));

__device__ __forceinline__ short f2bf(float f) {
    unsigned u = __builtin_bit_cast(unsigned, f);
    u = (u + 0x7fffu + ((u >> 16) & 1u)) >> 16;   // RNE
    return (short)u;
}
__device__ __forceinline__ float bf2f(short s) {
    unsigned u = ((unsigned)(unsigned short)s) << 16;
    return __builtin_bit_cast(float, u);
}

// ---------------- Kernel P: pack codebook (frag-order, TILE_C=32) + halfnorm
//                  + init acc + zero hist/cursor --------------------------------
__global__ __launch_bounds__(256)
void pack_kernel(const float* __restrict__ embed, short* __restrict__ ebf,
                 int* __restrict__ ghist, int* __restrict__ gcursor,
                 const float* __restrict__ ema_embed,
                 float* __restrict__ acc, float* __restrict__ hn)
{
    __shared__ float partial[256];
    const int t   = threadIdx.x;
    const int b   = blockIdx.x;
    const int g   = b * 256 + t;                      // 0..32767
    if (g < KCODES) { ghist[g] = 0; gcursor[g] = 0; }
    {   // init acc = 0.8 * ema_embed
        float4 e = reinterpret_cast<const float4*>(ema_embed)[g];
        float4 o = {0.8f * e.x, 0.8f * e.y, 0.8f * e.z, 0.8f * e.w};
        reinterpret_cast<float4*>(acc)[g] = o;
    }
    const int tc  = g >> 10;
    const int f   = (g >> 6) & 15;
    const int l   = g & 63;
    const int h   = f >> 3;
    const int nt  = (f >> 2) & 1;
    const int akk = f & 3;
    const int hg  = l >> 4;
    const int n   = l & 15;
    const int c   = tc * TILE_C + nt * 16 + n;
    const int d0  = akk * 32 + hg * 8;
    const float* src = embed + (long)c * DIM + d0;
    float4 v0 = *reinterpret_cast<const float4*>(src);
    float4 v1 = *reinterpret_cast<const float4*>(src + 4);
    float vv[8] = {v0.x, v0.y, v0.z, v0.w, v1.x, v1.y, v1.z, v1.w};
    bf16x8 out;
    float ss = 0.f;
    #pragma unroll
    for (int j = 0; j < 8; ++j) {
        short hi = f2bf(vv[j]);
        out[j] = h ? f2bf(vv[j] - bf2f(hi)) : hi;
        ss += vv[j] * vv[j];
    }
    *reinterpret_cast<bf16x8*>(ebf + (long)g * 8) = out;

    if (h == 0) {   // hi-blocks: 16 complete code rows -> halfnorm
        partial[t] = ss;
        __syncthreads();
        if (t < 16) {
            float s = 0.f;
            #pragma unroll
            for (int k = 0; k < 16; ++k) s += partial[t + k * 16];
            hn[tc * TILE_C + nt * 16 + t] = 0.5f * s;
        }
    }
}

// ---------------- Kernel 1: MFMA bf16x3 argmin, B streamed from L2 -------------
// grid (512, 2): x = point-block, y = codebook half. No LDS, no barriers.
__global__ __launch_bounds__(NTHR, 3)
void argmin_kernel(const float* __restrict__ x, const short* __restrict__ ebf,
                   const float* __restrict__ halfnorm, float2* __restrict__ bvbi)
{
    const int t    = threadIdx.x;
    const int lane = t & 63;
    const int w    = t >> 6;           // wave 0..3, owns 32 points
    const int r16  = lane & 15;
    const int h4   = lane >> 4;
    const int half = blockIdx.y;
    const long xbase = (long)blockIdx.x * BM * DIM;
    const int  wp    = w * 32;
    const int  cbase = half * HALF_C;
    // per-lane fragment stream: frag f lives at ebf[half*131072 + f*512 + lane*8]
    const bf16x8* B = reinterpret_cast<const bf16x8*>(
        ebf + (long)half * 16 * 8192 + lane * 8);

    // ---- A fragments: rows (wp + ms*16 + r16), hi/lo bf16 ----
    bf16x8 ahi[2][4], alo[2][4];
    #pragma unroll
    for (int ms = 0; ms < 2; ++ms) {
        const long prow = xbase + (long)(wp + ms * 16 + r16) * DIM;
        #pragma unroll
        for (int kk = 0; kk < 4; ++kk) {
            const float* s = x + prow + kk * 32 + h4 * 8;
            float4 u0 = *reinterpret_cast<const float4*>(s);
            float4 u1 = *reinterpret_cast<const float4*>(s + 4);
            float vv[8] = {u0.x, u0.y, u0.z, u0.w, u1.x, u1.y, u1.z, u1.w};
            #pragma unroll
            for (int j = 0; j < 8; ++j) {
                short hi = f2bf(vv[j]);
                ahi[ms][kk][j] = hi;
                alo[ms][kk][j] = f2bf(vv[j] - bf2f(hi));
            }
        }
    }

    float bestv[8];
    int   besti[8];
    #pragma unroll
    for (int s = 0; s < 8; ++s) { bestv[s] = -1e30f; besti[s] = 0; }

    #pragma unroll 4
    for (int tile = 0; tile < HALF_C / TILE_C; ++tile) {
        float hnv[2];
        #pragma unroll
        for (int nt = 0; nt < 2; ++nt)
            hnv[nt] = halfnorm[cbase + tile * TILE_C + nt * 16 + r16];

        f32x4 C[2][2];
        #pragma unroll
        for (int nt = 0; nt < 2; ++nt)
            #pragma unroll
            for (int ms = 0; ms < 2; ++ms) C[nt][ms] = (f32x4){0.f, 0.f, 0.f, 0.f};

        #pragma unroll
        for (int akk = 0; akk < 4; ++akk) {
            #pragma unroll
            for (int nt = 0; nt < 2; ++nt) {
                bf16x8 Bh = B[(tile * 16 + nt * 4 + akk) * 64];
                bf16x8 Bl = B[(tile * 16 + 8 + nt * 4 + akk) * 64];
                C[nt][0] = __builtin_amdgcn_mfma_f32_16x16x32_bf16(ahi[0][akk], Bh, C[nt][0], 0, 0, 0);
                C[nt][1] = __builtin_amdgcn_mfma_f32_16x16x32_bf16(ahi[1][akk], Bh, C[nt][1], 0, 0, 0);
                C[nt][0] = __builtin_amdgcn_mfma_f32_16x16x32_bf16(alo[0][akk], Bh, C[nt][0], 0, 0, 0);
                C[nt][1] = __builtin_amdgcn_mfma_f32_16x16x32_bf16(alo[1][akk], Bh, C[nt][1], 0, 0, 0);
                C[nt][0] = __builtin_amdgcn_mfma_f32_16x16x32_bf16(ahi[0][akk], Bl, C[nt][0], 0, 0, 0);
                C[nt][1] = __builtin_amdgcn_mfma_f32_16x16x32_bf16(ahi[1][akk], Bl, C[nt][1], 0, 0, 0);
            }
        }

        // ---- scores + running argmax (codes ascending per lane) ----
        #pragma unroll
        for (int nt = 0; nt < 2; ++nt) {
            const int c = cbase + tile * TILE_C + nt * 16 + r16;
            #pragma unroll
            for (int ms = 0; ms < 2; ++ms)
                #pragma unroll
                for (int reg = 0; reg < 4; ++reg) {
                    float sc  = C[nt][ms][reg] - hnv[nt];
                    int  slot = ms * 4 + reg;
                    if (sc > bestv[slot]) { bestv[slot] = sc; besti[slot] = c; }
                }
        }
    }

    // ---- butterfly reduce across 16 columns, tie -> smaller idx ----
    #pragma unroll
    for (int s = 0; s < 8; ++s) {
        float v = bestv[s];
        int   i = besti[s];
        #pragma unroll
        for (int off = 1; off < 16; off <<= 1) {
            float ov = __shfl_xor(v, off);
            int   oi = __shfl_xor(i, off);
            if (ov > v || (ov == v && oi < i)) { v = ov; i = oi; }
        }
        bestv[s] = v; besti[s] = i;
    }
    if (r16 == 0) {
        #pragma unroll
        for (int s = 0; s < 8; ++s) {
            int ms = s >> 2, reg = s & 3;
            int p  = wp + ms * 16 + h4 * 4 + reg;
            bvbi[(long)half * NPTS + blockIdx.x * BM + p] =
                (float2){bestv[s], __int_as_float(besti[s])};
        }
    }
}

// ---------------- Kernel M: merge halves + ind + quantize + histogram ----------
__global__ __launch_bounds__(256)
void merge_kernel(const float2* __restrict__ bvbi, const float* __restrict__ embed,
                  int* __restrict__ ind, float* __restrict__ quant,
                  int* __restrict__ ghist)
{
    __shared__ int hist[KCODES];
    __shared__ int bidx[256];
    const int t    = threadIdx.x;
    const int base = blockIdx.x * 256;

    for (int i = t; i < KCODES; i += 256) hist[i] = 0;

    float2 a = bvbi[base + t];
    float2 b = bvbi[NPTS + base + t];
    // half0 indices < half1 indices, so ties -> half0 = first occurrence
    const int best = (a.x >= b.x) ? __float_as_int(a.y) : __float_as_int(b.y);
    bidx[t] = best;
    ind[base + t] = best;
    __syncthreads();
    atomicAdd(&hist[best], 1);
    __syncthreads();
    for (int i = t; i < KCODES; i += 256)
        if (hist[i]) atomicAdd(&ghist[i], hist[i]);

    // quantize: lane-contiguous gather-copy of embed[best]
    float4* dst = reinterpret_cast<float4*>(quant + (long)base * DIM);
    #pragma unroll
    for (int i = 0; i < 32; ++i) {
        int idx = i * 256 + t;           // 0..8191
        int p   = idx >> 5;
        int q   = idx & 31;
        int c   = bidx[p];
        dst[idx] = reinterpret_cast<const float4*>(embed + (long)c * DIM)[q];
    }
}

// ---------------- Kernel C: scan(ghist) in-block + scatter + ema_num_new -------
__global__ __launch_bounds__(256)
void scatter_kernel(const int* __restrict__ ghist, const int* __restrict__ ind,
                    const float* __restrict__ ema_num, float* __restrict__ ema_num_new,
                    int* __restrict__ gcursor, int* __restrict__ sorted,
                    int* __restrict__ scode)
{
    __shared__ int off_lds[KCODES];
    __shared__ int wsum[4];
    const int t    = threadIdx.x;
    const int lane = t & 63;
    const int w    = t >> 6;

    int v[4], pre[4];
    int s = 0;
    #pragma unroll
    for (int j = 0; j < 4; ++j) {
        v[j] = ghist[t * 4 + j];
        pre[j] = s;
        s += v[j];
    }
    int incl = s;
    #pragma unroll
    for (int off = 1; off < 64; off <<= 1) {
        int u = __shfl_up(incl, off);
        if (lane >= off) incl += u;
    }
    if (lane == 63) wsum[w] = incl;
    __syncthreads();
    if (t == 0) {
        int a = 0;
        #pragma unroll
        for (int k = 0; k < 4; ++k) { int tmp = wsum[k]; wsum[k] = a; a += tmp; }
    }
    __syncthreads();
    const int excl = wsum[w] + incl - s;
    #pragma unroll
    for (int j = 0; j < 4; ++j) off_lds[t * 4 + j] = excl + pre[j];

    if (blockIdx.x == 0) {
        #pragma unroll
        for (int j = 0; j < 4; ++j)
            ema_num_new[t * 4 + j] = ema_num[t * 4 + j] * 0.8f + 0.2f * (float)v[j];
    }
    __syncthreads();

    const int p = blockIdx.x * 256 + t;
    const int c = ind[p];
    const int pos = off_lds[c] + atomicAdd(&gcursor[c], 1);
    sorted[pos] = p;
    scode[pos]  = c;
}

// ---------------- Kernel G: chunked run-sum over sorted order ------------------
__global__ __launch_bounds__(128)
void sum2_kernel(const float* __restrict__ x, const int* __restrict__ sorted,
                 const int* __restrict__ scode, float* __restrict__ acc)
{
    __shared__ int sp[64];
    __shared__ int sc[64];
    const int t = threadIdx.x;
    const int base = blockIdx.x * 64;
    if (t < 64) { sp[t] = sorted[base + t]; sc[t] = scode[base + t]; }
    __syncthreads();

    float a = 0.f;
    int cprev = sc[0];
    #pragma unroll 1
    for (int kk = 0; kk < 8; ++kk) {
        float v[8];
        #pragma unroll
        for (int i = 0; i < 8; ++i)
            v[i] = x[(long)sp[kk * 8 + i] * DIM + t];      // 8 independent 512B rows
        #pragma unroll
        for (int i = 0; i < 8; ++i) {
            const int c = sc[kk * 8 + i];                  // wave-uniform
            if (c != cprev) {
                atomicAdd(&acc[(long)cprev * DIM + t], 0.2f * a);
                a = 0.f; cprev = c;
            }
            a += v[i];
        }
    }
    atomicAdd(&acc[(long)cprev * DIM + t], 0.2f * a);
}

// ---------------- Kernel F: embed_new = ema_embed_new / ema_num_new ------------
__global__ __launch_bounds__(256)
void final_kernel(const float* __restrict__ acc, const float* __restrict__ ema_num_new,
                  float* __restrict__ embed_new)
{
    const int g = blockIdx.x * 256 + threadIdx.x;   // 0..32767 float4s
    float4 v = reinterpret_cast<const float4*>(acc)[g];
    const float en = ema_num_new[g >> 5];           // 32 float4s per code row
    float4 o = {v.x / en, v.y / en, v.z / en, v.w / en};
    reinterpret_cast<float4*>(embed_new)[g] = o;
}

extern "C" void kernel_launch(void* const* d_in, const int* in_sizes, int n_in,
                              void* d_out, int out_size, void* d_ws, size_t ws_size,
                              hipStream_t stream)
{
    const float* x         = (const float*)d_in[0];
    const float* embed     = (const float*)d_in[1];
    const float* ema_embed = (const float*)d_in[2];
    const float* ema_num   = (const float*)d_in[3];

    float* out0 = (float*)d_out;            // quantize      (16*4096*128)
    float* out1 = out0 + 8388608;           // embed_new     (1024*128)
    float* out2 = out1 + 131072;            // ema_embed_new (1024*128)
    float* out3 = out2 + 131072;            // ema_num_new   (1024)

    char*   ws      = (char*)d_ws;
    float*  hn      = (float*)ws;                   // 4 KB
    int*    ind     = (int*)(ws + 4096);            // 256 KB
    short*  ebf     = (short*)(ws + 266240);        // 512 KB
    int*    ghist   = (int*)(ws + 790528);          // 4 KB
    int*    gcursor = (int*)(ws + 794624);          // 4 KB
    float2* bvbi    = (float2*)(ws + 798720);       // 1 MB (dead after merge)
    int*    sorted  = (int*)(ws + 798720);          // 256 KB (reuses bvbi)
    int*    scode   = (int*)(ws + 1060864);         // 256 KB (reuses bvbi)

    pack_kernel<<<128, 256, 0, stream>>>(embed, ebf, ghist, gcursor, ema_embed, out2, hn);
    argmin_kernel<<<dim3(NPTS / BM, 2), NTHR, 0, stream>>>(x, ebf, hn, bvbi);
    merge_kernel<<<NPTS / 256, 256, 0, stream>>>(bvbi, embed, ind, out0, ghist);
    scatter_kernel<<<NPTS / 256, 256, 0, stream>>>(ghist, ind, ema_num, out3,
                                                   gcursor, sorted, scode);
    sum2_kernel<<<NPTS / 64, 128, 0, stream>>>(x, sorted, scode, out2);
    final_kernel<<<128, 256, 0, stream>>>(out2, out3, out1);
}

// Round 13
// 115.474 us; speedup vs baseline: 1.3286x; 1.3286x over previous
//
#include <hip/hip_runtime.h>

#define NPTS   65536
#define DIM    128
#define KCODES 1024
#define BM     128      // points per argmin block
#define TILE_C 32       // codes per LDS tile (16 KB each, 3-deep pipelined)
#define NTHR   256      // 4 waves; each wave owns 32 points (ms = 0,1)
#define HALF_C 512      // codes per argmin block (codebook split in 2)
#define NTILE  (HALF_C / TILE_C)   // 16

typedef short bf16x8 __attribute__((ext_vector_type(8)));
typedef float f32x4  __attribute__((ext_vector_type(4)));

__device__ __forceinline__ short f2bf(float f) {
    unsigned u = __builtin_bit_cast(unsigned, f);
    u = (u + 0x7fffu + ((u >> 16) & 1u)) >> 16;   // RNE
    return (short)u;
}
__device__ __forceinline__ float bf2f(short s) {
    unsigned u = ((unsigned)(unsigned short)s) << 16;
    return __builtin_bit_cast(float, u);
}
__device__ __forceinline__ void gload_lds16(const void* g, void* l) {
    __builtin_amdgcn_global_load_lds(
        (const __attribute__((address_space(1))) void*)g,
        (__attribute__((address_space(3))) void*)l, 16, 0, 0);
}

// ---------------- Kernel P: pack codebook (frag-order, TILE_C=32) + halfnorm
//                  + init acc + zero hist/cursor --------------------------------
__global__ __launch_bounds__(256)
void pack_kernel(const float* __restrict__ embed, short* __restrict__ ebf,
                 int* __restrict__ ghist, int* __restrict__ gcursor,
                 const float* __restrict__ ema_embed,
                 float* __restrict__ acc, float* __restrict__ hn)
{
    __shared__ float partial[256];
    const int t   = threadIdx.x;
    const int b   = blockIdx.x;
    const int g   = b * 256 + t;                      // 0..32767
    if (g < KCODES) { ghist[g] = 0; gcursor[g] = 0; }
    {   // init acc = 0.8 * ema_embed
        float4 e = reinterpret_cast<const float4*>(ema_embed)[g];
        float4 o = {0.8f * e.x, 0.8f * e.y, 0.8f * e.z, 0.8f * e.w};
        reinterpret_cast<float4*>(acc)[g] = o;
    }
    const int tc  = g >> 10;
    const int f   = (g >> 6) & 15;
    const int l   = g & 63;
    const int h   = f >> 3;
    const int nt  = (f >> 2) & 1;
    const int akk = f & 3;
    const int hg  = l >> 4;
    const int n   = l & 15;
    const int c   = tc * TILE_C + nt * 16 + n;
    const int d0  = akk * 32 + hg * 8;
    const float* src = embed + (long)c * DIM + d0;
    float4 v0 = *reinterpret_cast<const float4*>(src);
    float4 v1 = *reinterpret_cast<const float4*>(src + 4);
    float vv[8] = {v0.x, v0.y, v0.z, v0.w, v1.x, v1.y, v1.z, v1.w};
    bf16x8 out;
    float ss = 0.f;
    #pragma unroll
    for (int j = 0; j < 8; ++j) {
        short hi = f2bf(vv[j]);
        out[j] = h ? f2bf(vv[j] - bf2f(hi)) : hi;
        ss += vv[j] * vv[j];
    }
    *reinterpret_cast<bf16x8*>(ebf + (long)g * 8) = out;

    if (h == 0) {   // hi-blocks: 16 complete code rows -> halfnorm
        partial[t] = ss;
        __syncthreads();
        if (t < 16) {
            float s = 0.f;
            #pragma unroll
            for (int k = 0; k < 16; ++k) s += partial[t + k * 16];
            hn[tc * TILE_C + nt * 16 + t] = 0.5f * s;
        }
    }
}

// ---------------- Kernel 1: MFMA bf16x3 argmin, 3-deep LDS pipeline ------------
// grid (512, 2). Raw barriers + counted vmcnt — no full drain in the loop.
__global__ __launch_bounds__(NTHR, 2)
void argmin_kernel(const float* __restrict__ x, const short* __restrict__ ebf,
                   const float* __restrict__ halfnorm, float2* __restrict__ bvbi)
{
    __shared__ short es[3][8192];       // 3 x 16 KB pipelined tiles

    const int t    = threadIdx.x;
    const int lane = t & 63;
    const int w    = t >> 6;           // wave 0..3, owns 32 points
    const int r16  = lane & 15;
    const int h4   = lane >> 4;
    const int half = blockIdx.y;
    const long xbase = (long)blockIdx.x * BM * DIM;
    const int  wp    = w * 32;
    const int  cbase = half * HALF_C;
    const short* eb  = ebf + (long)half * 16 * 8192;   // this half's packed base

    // ---- A fragments: rows (wp + ms*16 + r16), hi/lo bf16 ----
    bf16x8 ahi[2][4], alo[2][4];
    #pragma unroll
    for (int ms = 0; ms < 2; ++ms) {
        const long prow = xbase + (long)(wp + ms * 16 + r16) * DIM;
        #pragma unroll
        for (int kk = 0; kk < 4; ++kk) {
            const float* s = x + prow + kk * 32 + h4 * 8;
            float4 u0 = *reinterpret_cast<const float4*>(s);
            float4 u1 = *reinterpret_cast<const float4*>(s + 4);
            float vv[8] = {u0.x, u0.y, u0.z, u0.w, u1.x, u1.y, u1.z, u1.w};
            #pragma unroll
            for (int j = 0; j < 8; ++j) {
                short hi = f2bf(vv[j]);
                ahi[ms][kk][j] = hi;
                alo[ms][kk][j] = f2bf(vv[j] - bf2f(hi));
            }
        }
    }

    // ---- prologue: stage tiles 0,1 and hnv(0) ----
    #pragma unroll
    for (int i = 0; i < 4; ++i) {
        const int f = w * 4 + i;
        gload_lds16(eb + (long)f * 512 + lane * 8, &es[0][f * 512]);
    }
    #pragma unroll
    for (int i = 0; i < 4; ++i) {
        const int f = w * 4 + i;
        gload_lds16(eb + (long)8192 + f * 512 + lane * 8, &es[1][f * 512]);
    }
    float hnv_cur[2], hnv_nxt[2];
    #pragma unroll
    for (int nt = 0; nt < 2; ++nt) hnv_cur[nt] = halfnorm[cbase + nt * 16 + r16];

    float bestv[8];
    int   besti[8];
    #pragma unroll
    for (int s = 0; s < 8; ++s) { bestv[s] = -1e30f; besti[s] = 0; }

    int ia = 0, ic = 2;   // ia = compute buf (tile t), ic = stage target (t+2)

    #pragma unroll 1
    for (int tile = 0; tile < NTILE; ++tile) {
        // bar1: all waves done computing tile-1 (es[ic]'s old contents free)
        __builtin_amdgcn_s_barrier();

        if (tile + 2 < NTILE) {
            const long gbase = (long)(tile + 2) * 8192;
            #pragma unroll
            for (int i = 0; i < 4; ++i) {
                const int f = w * 4 + i;
                gload_lds16(eb + gbase + f * 512 + lane * 8, &es[ic][f * 512]);
            }
        }
        if (tile + 1 < NTILE) {
            #pragma unroll
            for (int nt = 0; nt < 2; ++nt)
                hnv_nxt[nt] = halfnorm[cbase + (tile + 1) * TILE_C + nt * 16 + r16];
        }

        // counted wait: tile's stage (2 iters old) + hnv(tile) (1 iter old) done
        if (tile < NTILE - 2)       asm volatile("s_waitcnt vmcnt(6)" ::: "memory");
        else if (tile == NTILE - 2) asm volatile("s_waitcnt vmcnt(2)" ::: "memory");
        else                        asm volatile("s_waitcnt vmcnt(0)" ::: "memory");

        // bar2: every wave's tile-t loads are resident
        __builtin_amdgcn_s_barrier();

        f32x4 C[2][2];
        #pragma unroll
        for (int nt = 0; nt < 2; ++nt)
            #pragma unroll
            for (int ms = 0; ms < 2; ++ms) C[nt][ms] = (f32x4){0.f, 0.f, 0.f, 0.f};

        #pragma unroll
        for (int akk = 0; akk < 4; ++akk) {
            #pragma unroll
            for (int nt = 0; nt < 2; ++nt) {
                bf16x8 Bh = *reinterpret_cast<const bf16x8*>(&es[ia][(nt * 4 + akk) * 512 + lane * 8]);
                bf16x8 Bl = *reinterpret_cast<const bf16x8*>(&es[ia][(8 + nt * 4 + akk) * 512 + lane * 8]);
                C[nt][0] = __builtin_amdgcn_mfma_f32_16x16x32_bf16(ahi[0][akk], Bh, C[nt][0], 0, 0, 0);
                C[nt][1] = __builtin_amdgcn_mfma_f32_16x16x32_bf16(ahi[1][akk], Bh, C[nt][1], 0, 0, 0);
                C[nt][0] = __builtin_amdgcn_mfma_f32_16x16x32_bf16(alo[0][akk], Bh, C[nt][0], 0, 0, 0);
                C[nt][1] = __builtin_amdgcn_mfma_f32_16x16x32_bf16(alo[1][akk], Bh, C[nt][1], 0, 0, 0);
                C[nt][0] = __builtin_amdgcn_mfma_f32_16x16x32_bf16(ahi[0][akk], Bl, C[nt][0], 0, 0, 0);
                C[nt][1] = __builtin_amdgcn_mfma_f32_16x16x32_bf16(ahi[1][akk], Bl, C[nt][1], 0, 0, 0);
            }
        }

        // ---- scores + running argmax (codes ascending per lane) ----
        #pragma unroll
        for (int nt = 0; nt < 2; ++nt) {
            const int c = cbase + tile * TILE_C + nt * 16 + r16;
            #pragma unroll
            for (int ms = 0; ms < 2; ++ms)
                #pragma unroll
                for (int reg = 0; reg < 4; ++reg) {
                    float sc  = C[nt][ms][reg] - hnv_cur[nt];
                    int  slot = ms * 4 + reg;
                    if (sc > bestv[slot]) { bestv[slot] = sc; besti[slot] = c; }
                }
        }
        hnv_cur[0] = hnv_nxt[0];
        hnv_cur[1] = hnv_nxt[1];
        // rotate buffer indices: (ia, ib, ic) <- (ib, ic, ia)
        int tmp = ia;
        ia = (ia + 1) % 3;
        ic = (ic + 1) % 3;
        (void)tmp;
    }

    // ---- butterfly reduce across 16 columns, tie -> smaller idx ----
    #pragma unroll
    for (int s = 0; s < 8; ++s) {
        float v = bestv[s];
        int   i = besti[s];
        #pragma unroll
        for (int off = 1; off < 16; off <<= 1) {
            float ov = __shfl_xor(v, off);
            int   oi = __shfl_xor(i, off);
            if (ov > v || (ov == v && oi < i)) { v = ov; i = oi; }
        }
        bestv[s] = v; besti[s] = i;
    }
    if (r16 == 0) {
        #pragma unroll
        for (int s = 0; s < 8; ++s) {
            int ms = s >> 2, reg = s & 3;
            int p  = wp + ms * 16 + h4 * 4 + reg;
            bvbi[(long)half * NPTS + blockIdx.x * BM + p] =
                (float2){bestv[s], __int_as_float(besti[s])};
        }
    }
}

// ---------------- Kernel M: merge halves + ind + quantize + histogram ----------
__global__ __launch_bounds__(256)
void merge_kernel(const float2* __restrict__ bvbi, const float* __restrict__ embed,
                  int* __restrict__ ind, float* __restrict__ quant,
                  int* __restrict__ ghist)
{
    __shared__ int hist[KCODES];
    __shared__ int bidx[256];
    const int t    = threadIdx.x;
    const int base = blockIdx.x * 256;

    for (int i = t; i < KCODES; i += 256) hist[i] = 0;

    float2 a = bvbi[base + t];
    float2 b = bvbi[NPTS + base + t];
    // half0 indices < half1 indices, so ties -> half0 = first occurrence
    const int best = (a.x >= b.x) ? __float_as_int(a.y) : __float_as_int(b.y);
    bidx[t] = best;
    ind[base + t] = best;
    __syncthreads();
    atomicAdd(&hist[best], 1);
    __syncthreads();
    for (int i = t; i < KCODES; i += 256)
        if (hist[i]) atomicAdd(&ghist[i], hist[i]);

    // quantize: lane-contiguous gather-copy of embed[best]
    float4* dst = reinterpret_cast<float4*>(quant + (long)base * DIM);
    #pragma unroll
    for (int i = 0; i < 32; ++i) {
        int idx = i * 256 + t;           // 0..8191
        int p   = idx >> 5;
        int q   = idx & 31;
        int c   = bidx[p];
        dst[idx] = reinterpret_cast<const float4*>(embed + (long)c * DIM)[q];
    }
}

// ---------------- Kernel C: scan(ghist) in-block + scatter + ema_num_new -------
__global__ __launch_bounds__(256)
void scatter_kernel(const int* __restrict__ ghist, const int* __restrict__ ind,
                    const float* __restrict__ ema_num, float* __restrict__ ema_num_new,
                    int* __restrict__ gcursor, int* __restrict__ sorted,
                    int* __restrict__ scode)
{
    __shared__ int off_lds[KCODES];
    __shared__ int wsum[4];
    const int t    = threadIdx.x;
    const int lane = t & 63;
    const int w    = t >> 6;

    int v[4], pre[4];
    int s = 0;
    #pragma unroll
    for (int j = 0; j < 4; ++j) {
        v[j] = ghist[t * 4 + j];
        pre[j] = s;
        s += v[j];
    }
    int incl = s;
    #pragma unroll
    for (int off = 1; off < 64; off <<= 1) {
        int u = __shfl_up(incl, off);
        if (lane >= off) incl += u;
    }
    if (lane == 63) wsum[w] = incl;
    __syncthreads();
    if (t == 0) {
        int a = 0;
        #pragma unroll
        for (int k = 0; k < 4; ++k) { int tmp = wsum[k]; wsum[k] = a; a += tmp; }
    }
    __syncthreads();
    const int excl = wsum[w] + incl - s;
    #pragma unroll
    for (int j = 0; j < 4; ++j) off_lds[t * 4 + j] = excl + pre[j];

    if (blockIdx.x == 0) {
        #pragma unroll
        for (int j = 0; j < 4; ++j)
            ema_num_new[t * 4 + j] = ema_num[t * 4 + j] * 0.8f + 0.2f * (float)v[j];
    }
    __syncthreads();

    const int p = blockIdx.x * 256 + t;
    const int c = ind[p];
    const int pos = off_lds[c] + atomicAdd(&gcursor[c], 1);
    sorted[pos] = p;
    scode[pos]  = c;
}

// ---------------- Kernel G: chunked run-sum over sorted order ------------------
__global__ __launch_bounds__(128)
void sum2_kernel(const float* __restrict__ x, const int* __restrict__ sorted,
                 const int* __restrict__ scode, float* __restrict__ acc)
{
    __shared__ int sp[64];
    __shared__ int sc[64];
    const int t = threadIdx.x;
    const int base = blockIdx.x * 64;
    if (t < 64) { sp[t] = sorted[base + t]; sc[t] = scode[base + t]; }
    __syncthreads();

    float a = 0.f;
    int cprev = sc[0];
    #pragma unroll 1
    for (int kk = 0; kk < 8; ++kk) {
        float v[8];
        #pragma unroll
        for (int i = 0; i < 8; ++i)
            v[i] = x[(long)sp[kk * 8 + i] * DIM + t];      // 8 independent 512B rows
        #pragma unroll
        for (int i = 0; i < 8; ++i) {
            const int c = sc[kk * 8 + i];                  // wave-uniform
            if (c != cprev) {
                atomicAdd(&acc[(long)cprev * DIM + t], 0.2f * a);
                a = 0.f; cprev = c;
            }
            a += v[i];
        }
    }
    atomicAdd(&acc[(long)cprev * DIM + t], 0.2f * a);
}

// ---------------- Kernel F: embed_new = ema_embed_new / ema_num_new ------------
__global__ __launch_bounds__(256)
void final_kernel(const float* __restrict__ acc, const float* __restrict__ ema_num_new,
                  float* __restrict__ embed_new)
{
    const int g = blockIdx.x * 256 + threadIdx.x;   // 0..32767 float4s
    float4 v = reinterpret_cast<const float4*>(acc)[g];
    const float en = ema_num_new[g >> 5];           // 32 float4s per code row
    float4 o = {v.x / en, v.y / en, v.z / en, v.w / en};
    reinterpret_cast<float4*>(embed_new)[g] = o;
}

extern "C" void kernel_launch(void* const* d_in, const int* in_sizes, int n_in,
                              void* d_out, int out_size, void* d_ws, size_t ws_size,
                              hipStream_t stream)
{
    const float* x         = (const float*)d_in[0];
    const float* embed     = (const float*)d_in[1];
    const float* ema_embed = (const float*)d_in[2];
    const float* ema_num   = (const float*)d_in[3];

    float* out0 = (float*)d_out;            // quantize      (16*4096*128)
    float* out1 = out0 + 8388608;           // embed_new     (1024*128)
    float* out2 = out1 + 131072;            // ema_embed_new (1024*128)
    float* out3 = out2 + 131072;            // ema_num_new   (1024)

    char*   ws      = (char*)d_ws;
    float*  hn      = (float*)ws;                   // 4 KB
    int*    ind     = (int*)(ws + 4096);            // 256 KB
    short*  ebf     = (short*)(ws + 266240);        // 512 KB
    int*    ghist   = (int*)(ws + 790528);          // 4 KB
    int*    gcursor = (int*)(ws + 794624);          // 4 KB
    float2* bvbi    = (float2*)(ws + 798720);       // 1 MB (dead after merge)
    int*    sorted  = (int*)(ws + 798720);          // 256 KB (reuses bvbi)
    int*    scode   = (int*)(ws + 1060864);         // 256 KB (reuses bvbi)

    pack_kernel<<<128, 256, 0, stream>>>(embed, ebf, ghist, gcursor, ema_embed, out2, hn);
    argmin_kernel<<<dim3(NPTS / BM, 2), NTHR, 0, stream>>>(x, ebf, hn, bvbi);
    merge_kernel<<<NPTS / 256, 256, 0, stream>>>(bvbi, embed, ind, out0, ghist);
    scatter_kernel<<<NPTS / 256, 256, 0, stream>>>(ghist, ind, ema_num, out3,
                                                   gcursor, sorted, scode);
    sum2_kernel<<<NPTS / 64, 128, 0, stream>>>(x, sorted, scode, out2);
    final_kernel<<<128, 256, 0, stream>>>(out2, out3, out1);
}

// Round 14
// 100.325 us; speedup vs baseline: 1.5292x; 1.1510x over previous
//
#include <hip/hip_runtime.h>

#define NPTS    65536
#define DIM     128
#define KCODES  1024
#define BM      128      // points per argmin block
#define TILE_C  64       // codes per LDS tile
#define NTHR    256      // 4 waves; each wave owns 32 points (ms = 0,1)
#define QUART_C 256      // codes per argmin block (codebook split in 4)
#define NTILE   (QUART_C / TILE_C)   // 4

typedef _Float16 f16x8 __attribute__((ext_vector_type(8)));
typedef float    f32x4 __attribute__((ext_vector_type(4)));

__device__ __forceinline__ void gload_lds16(const void* g, void* l) {
    __builtin_amdgcn_global_load_lds(
        (const __attribute__((address_space(1))) void*)g,
        (__attribute__((address_space(3))) void*)l, 16, 0, 0);
}
// order-preserving float->u32 (monotone increasing)
__device__ __forceinline__ unsigned mono32(float f) {
    unsigned u = __builtin_bit_cast(unsigned, f);
    return (u & 0x80000000u) ? ~u : (u | 0x80000000u);
}

// ---------------- Kernel P: pack codebook -> fp16 frag-order + halfnorm(rounded)
//                  + init acc/ghist/gcursor/kmax --------------------------------
// 64 blocks x 256. g in 0..16383: tc=g>>10, f=(g>>6)&15, l=g&63;
// f = nt*4+akk ; l = hg*16+n ; code c = tc*64+nt*16+n ; d0 = akk*32+hg*8.
__global__ __launch_bounds__(256)
void pack_kernel(const float* __restrict__ embed, _Float16* __restrict__ ebf,
                 int* __restrict__ ghist, int* __restrict__ gcursor,
                 const float* __restrict__ ema_embed, float* __restrict__ acc,
                 float* __restrict__ hn, unsigned long long* __restrict__ kmax)
{
    __shared__ float partial[256];
    const int t = threadIdx.x;
    const int b = blockIdx.x;
    const int g = b * 256 + t;                       // 0..16383
    if (g < KCODES) { ghist[g] = 0; gcursor[g] = 0; }
    {   // init acc = 0.8 * ema_embed (2 float4s per thread = 32768 total)
        float4 e0 = reinterpret_cast<const float4*>(ema_embed)[g];
        float4 e1 = reinterpret_cast<const float4*>(ema_embed)[g + 16384];
        reinterpret_cast<float4*>(acc)[g] =
            (float4){0.8f * e0.x, 0.8f * e0.y, 0.8f * e0.z, 0.8f * e0.w};
        reinterpret_cast<float4*>(acc)[g + 16384] =
            (float4){0.8f * e1.x, 0.8f * e1.y, 0.8f * e1.z, 0.8f * e1.w};
    }
    #pragma unroll
    for (int k = 0; k < 4; ++k) kmax[g * 4 + k] = 0ull;   // keys are always > 0

    const int tc  = g >> 10;
    const int f   = (g >> 6) & 15;
    const int l   = g & 63;
    const int nt  = f >> 2;
    const int akk = f & 3;
    const int hg  = l >> 4;
    const int n   = l & 15;
    const int c   = tc * TILE_C + nt * 16 + n;
    const int d0  = akk * 32 + hg * 8;
    const float* src = embed + (long)c * DIM + d0;
    float4 v0 = *reinterpret_cast<const float4*>(src);
    float4 v1 = *reinterpret_cast<const float4*>(src + 4);
    float vv[8] = {v0.x, v0.y, v0.z, v0.w, v1.x, v1.y, v1.z, v1.w};
    f16x8 out;
    float ss = 0.f;
    #pragma unroll
    for (int j = 0; j < 8; ++j) {
        _Float16 h = (_Float16)vv[j];                // RNE
        out[j] = h;
        float r = (float)h;                          // halfnorm from ROUNDED values
        ss += r * r;
    }
    *reinterpret_cast<f16x8*>(ebf + (long)g * 8) = out;

    // block b holds 16 complete code rows (tc=b>>2, nt=b&3)
    partial[t] = ss;
    __syncthreads();
    if (t < 16) {
        float s = 0.f;
        #pragma unroll
        for (int k = 0; k < 16; ++k) s += partial[t + k * 16];
        hn[(b >> 2) * TILE_C + (b & 3) * 16 + t] = 0.5f * s;
    }
}

// ---------------- Kernel 1: MFMA fp16 argmin over a QUARTER of the codebook ----
// grid (512, 4). score = x_hat . e_hat - 0.5||e_hat||^2  (exact in rounded space)
__global__ __launch_bounds__(NTHR, 4)
void argmin_kernel(const float* __restrict__ x, const _Float16* __restrict__ ebf,
                   const float* __restrict__ halfnorm,
                   unsigned long long* __restrict__ kmax)
{
    __shared__ _Float16 es[2][8192];    // 2 x 16 KB double-buffered tile

    const int t     = threadIdx.x;
    const int lane  = t & 63;
    const int w     = t >> 6;          // wave 0..3, owns 32 points
    const int r16   = lane & 15;
    const int h4    = lane >> 4;
    const int quart = blockIdx.y;
    const long xbase = (long)blockIdx.x * BM * DIM;
    const int  wp    = w * 32;
    const int  qbase = quart * QUART_C;
    const _Float16* eb = ebf + (long)quart * QUART_C * DIM;   // quarter base

    // ---- A fragments: rows (wp + ms*16 + r16), fp16 ----
    f16x8 a[2][4];
    #pragma unroll
    for (int ms = 0; ms < 2; ++ms) {
        const long prow = xbase + (long)(wp + ms * 16 + r16) * DIM;
        #pragma unroll
        for (int akk = 0; akk < 4; ++akk) {
            const float* s = x + prow + akk * 32 + h4 * 8;
            float4 u0 = *reinterpret_cast<const float4*>(s);
            float4 u1 = *reinterpret_cast<const float4*>(s + 4);
            float vv[8] = {u0.x, u0.y, u0.z, u0.w, u1.x, u1.y, u1.z, u1.w};
            #pragma unroll
            for (int j = 0; j < 8; ++j) a[ms][akk][j] = (_Float16)vv[j];
        }
    }

    // ---- prologue: stage tile 0 (wave w loads frags w*4..w*4+3, 1 KB each) ----
    #pragma unroll
    for (int i = 0; i < 4; ++i) {
        const int f = w * 4 + i;
        gload_lds16(eb + (long)f * 512 + lane * 8, &es[0][f * 512]);
    }
    float hnv_cur[4], hnv_nxt[4];
    #pragma unroll
    for (int nt = 0; nt < 4; ++nt) hnv_cur[nt] = halfnorm[qbase + nt * 16 + r16];
    __syncthreads();   // tile 0 resident

    float bestv[8];
    int   besti[8];
    #pragma unroll
    for (int s = 0; s < 8; ++s) { bestv[s] = -1e30f; besti[s] = 0; }

    #pragma unroll 1
    for (int tile = 0; tile < NTILE; ++tile) {
        // issue next tile's stage + next halfnorms (latency hides under MFMA)
        if (tile + 1 < NTILE) {
            const long gbase = (long)(tile + 1) * 8192;
            #pragma unroll
            for (int i = 0; i < 4; ++i) {
                const int f = w * 4 + i;
                gload_lds16(eb + gbase + f * 512 + lane * 8, &es[(tile + 1) & 1][f * 512]);
            }
            #pragma unroll
            for (int nt = 0; nt < 4; ++nt)
                hnv_nxt[nt] = halfnorm[qbase + (tile + 1) * TILE_C + nt * 16 + r16];
        }

        f32x4 C[4][2];
        #pragma unroll
        for (int nt = 0; nt < 4; ++nt)
            #pragma unroll
            for (int ms = 0; ms < 2; ++ms) C[nt][ms] = (f32x4){0.f, 0.f, 0.f, 0.f};

        #pragma unroll
        for (int akk = 0; akk < 4; ++akk) {
            #pragma unroll
            for (int nt = 0; nt < 4; ++nt) {
                f16x8 B = *reinterpret_cast<const f16x8*>(
                    &es[tile & 1][(nt * 4 + akk) * 512 + lane * 8]);
                C[nt][0] = __builtin_amdgcn_mfma_f32_16x16x32_f16(a[0][akk], B, C[nt][0], 0, 0, 0);
                C[nt][1] = __builtin_amdgcn_mfma_f32_16x16x32_f16(a[1][akk], B, C[nt][1], 0, 0, 0);
            }
        }

        // ---- scores + running argmax (codes ascending: tile asc, nt asc) ----
        #pragma unroll
        for (int nt = 0; nt < 4; ++nt) {
            const int c = qbase + tile * TILE_C + nt * 16 + r16;
            #pragma unroll
            for (int ms = 0; ms < 2; ++ms)
                #pragma unroll
                for (int reg = 0; reg < 4; ++reg) {
                    float sc  = C[nt][ms][reg] - hnv_cur[nt];
                    int  slot = ms * 4 + reg;
                    if (sc > bestv[slot]) { bestv[slot] = sc; besti[slot] = c; }
                }
        }
        #pragma unroll
        for (int nt = 0; nt < 4; ++nt) hnv_cur[nt] = hnv_nxt[nt];
        __syncthreads();   // next tile resident; current tile readers done
    }

    // ---- butterfly reduce across 16 columns, tie -> smaller idx ----
    #pragma unroll
    for (int s = 0; s < 8; ++s) {
        float v = bestv[s];
        int   i = besti[s];
        #pragma unroll
        for (int off = 1; off < 16; off <<= 1) {
            float ov = __shfl_xor(v, off);
            int   oi = __shfl_xor(i, off);
            if (ov > v || (ov == v && oi < i)) { v = ov; i = oi; }
        }
        bestv[s] = v; besti[s] = i;
    }
    // deterministic cross-quarter merge: atomicMax on packed key
    if (r16 == 0) {
        #pragma unroll
        for (int s = 0; s < 8; ++s) {
            int ms = s >> 2, reg = s & 3;
            int p  = wp + ms * 16 + h4 * 4 + reg;
            unsigned long long key =
                ((unsigned long long)mono32(bestv[s]) << 32) |
                (unsigned long long)(0x3FFu - (unsigned)besti[s]);
            atomicMax(&kmax[blockIdx.x * BM + p], key);
        }
    }
}

// ---------------- Kernel M: extract idx + ind + quantize + histogram -----------
__global__ __launch_bounds__(256)
void merge_kernel(const unsigned long long* __restrict__ kmax,
                  const float* __restrict__ embed, int* __restrict__ ind,
                  float* __restrict__ quant, int* __restrict__ ghist)
{
    __shared__ int hist[KCODES];
    __shared__ int bidx[256];
    const int t    = threadIdx.x;
    const int base = blockIdx.x * 256;

    for (int i = t; i < KCODES; i += 256) hist[i] = 0;

    const unsigned long long k = kmax[base + t];
    const int best = 0x3FF - (int)(k & 0x3FFu);
    bidx[t] = best;
    ind[base + t] = best;
    __syncthreads();
    atomicAdd(&hist[best], 1);
    __syncthreads();
    for (int i = t; i < KCODES; i += 256)
        if (hist[i]) atomicAdd(&ghist[i], hist[i]);

    // quantize: lane-contiguous gather-copy of embed[best]
    float4* dst = reinterpret_cast<float4*>(quant + (long)base * DIM);
    #pragma unroll
    for (int i = 0; i < 32; ++i) {
        int idx = i * 256 + t;           // 0..8191
        int p   = idx >> 5;
        int q   = idx & 31;
        int c   = bidx[p];
        dst[idx] = reinterpret_cast<const float4*>(embed + (long)c * DIM)[q];
    }
}

// ---------------- Kernel C: scan(ghist) in-block + scatter + ema_num_new -------
__global__ __launch_bounds__(256)
void scatter_kernel(const int* __restrict__ ghist, const int* __restrict__ ind,
                    const float* __restrict__ ema_num, float* __restrict__ ema_num_new,
                    int* __restrict__ gcursor, int* __restrict__ sorted,
                    int* __restrict__ scode)
{
    __shared__ int off_lds[KCODES];
    __shared__ int wsum[4];
    const int t    = threadIdx.x;
    const int lane = t & 63;
    const int w    = t >> 6;

    int v[4], pre[4];
    int s = 0;
    #pragma unroll
    for (int j = 0; j < 4; ++j) {
        v[j] = ghist[t * 4 + j];
        pre[j] = s;
        s += v[j];
    }
    int incl = s;
    #pragma unroll
    for (int off = 1; off < 64; off <<= 1) {
        int u = __shfl_up(incl, off);
        if (lane >= off) incl += u;
    }
    if (lane == 63) wsum[w] = incl;
    __syncthreads();
    if (t == 0) {
        int a = 0;
        #pragma unroll
        for (int k = 0; k < 4; ++k) { int tmp = wsum[k]; wsum[k] = a; a += tmp; }
    }
    __syncthreads();
    const int excl = wsum[w] + incl - s;
    #pragma unroll
    for (int j = 0; j < 4; ++j) off_lds[t * 4 + j] = excl + pre[j];

    if (blockIdx.x == 0) {
        #pragma unroll
        for (int j = 0; j < 4; ++j)
            ema_num_new[t * 4 + j] = ema_num[t * 4 + j] * 0.8f + 0.2f * (float)v[j];
    }
    __syncthreads();

    const int p = blockIdx.x * 256 + t;
    const int c = ind[p];
    const int pos = off_lds[c] + atomicAdd(&gcursor[c], 1);
    sorted[pos] = p;
    scode[pos]  = c;
}

// ---------------- Kernel G: chunked run-sum over sorted order ------------------
__global__ __launch_bounds__(128)
void sum2_kernel(const float* __restrict__ x, const int* __restrict__ sorted,
                 const int* __restrict__ scode, float* __restrict__ acc)
{
    __shared__ int sp[64];
    __shared__ int sc[64];
    const int t = threadIdx.x;
    const int base = blockIdx.x * 64;
    if (t < 64) { sp[t] = sorted[base + t]; sc[t] = scode[base + t]; }
    __syncthreads();

    float a = 0.f;
    int cprev = sc[0];
    #pragma unroll 1
    for (int kk = 0; kk < 8; ++kk) {
        float v[8];
        #pragma unroll
        for (int i = 0; i < 8; ++i)
            v[i] = x[(long)sp[kk * 8 + i] * DIM + t];      // 8 independent 512B rows
        #pragma unroll
        for (int i = 0; i < 8; ++i) {
            const int c = sc[kk * 8 + i];                  // wave-uniform
            if (c != cprev) {
                atomicAdd(&acc[(long)cprev * DIM + t], 0.2f * a);
                a = 0.f; cprev = c;
            }
            a += v[i];
        }
    }
    atomicAdd(&acc[(long)cprev * DIM + t], 0.2f * a);
}

// ---------------- Kernel F: embed_new = ema_embed_new / ema_num_new ------------
__global__ __launch_bounds__(256)
void final_kernel(const float* __restrict__ acc, const float* __restrict__ ema_num_new,
                  float* __restrict__ embed_new)
{
    const int g = blockIdx.x * 256 + threadIdx.x;   // 0..32767 float4s
    float4 v = reinterpret_cast<const float4*>(acc)[g];
    const float en = ema_num_new[g >> 5];           // 32 float4s per code row
    float4 o = {v.x / en, v.y / en, v.z / en, v.w / en};
    reinterpret_cast<float4*>(embed_new)[g] = o;
}

extern "C" void kernel_launch(void* const* d_in, const int* in_sizes, int n_in,
                              void* d_out, int out_size, void* d_ws, size_t ws_size,
                              hipStream_t stream)
{
    const float* x         = (const float*)d_in[0];
    const float* embed     = (const float*)d_in[1];
    const float* ema_embed = (const float*)d_in[2];
    const float* ema_num   = (const float*)d_in[3];

    float* out0 = (float*)d_out;            // quantize      (16*4096*128)
    float* out1 = out0 + 8388608;           // embed_new     (1024*128)
    float* out2 = out1 + 131072;            // ema_embed_new (1024*128)
    float* out3 = out2 + 131072;            // ema_num_new   (1024)

    char* ws = (char*)d_ws;
    float*              hn      = (float*)ws;                     // 4 KB
    int*                ind     = (int*)(ws + 4096);              // 256 KB
    _Float16*           ebf     = (_Float16*)(ws + 266240);       // 256 KB
    int*                ghist   = (int*)(ws + 528384);            // 4 KB
    int*                gcursor = (int*)(ws + 532480);            // 4 KB
    unsigned long long* kmax    = (unsigned long long*)(ws + 536576); // 512 KB (dead after merge)
    int*                sorted  = (int*)(ws + 536576);            // 256 KB (overlays kmax)
    int*                scode   = (int*)(ws + 798720);            // 256 KB (overlays kmax)

    pack_kernel<<<64, 256, 0, stream>>>(embed, ebf, ghist, gcursor, ema_embed,
                                        out2, hn, kmax);
    argmin_kernel<<<dim3(NPTS / BM, 4), NTHR, 0, stream>>>(x, ebf, hn, kmax);
    merge_kernel<<<NPTS / 256, 256, 0, stream>>>(kmax, embed, ind, out0, ghist);
    scatter_kernel<<<NPTS / 256, 256, 0, stream>>>(ghist, ind, ema_num, out3,
                                                   gcursor, sorted, scode);
    sum2_kernel<<<NPTS / 64, 128, 0, stream>>>(x, sorted, scode, out2);
    final_kernel<<<128, 256, 0, stream>>>(out2, out3, out1);
}

// Round 15
// 96.132 us; speedup vs baseline: 1.5959x; 1.0436x over previous
//
#include <hip/hip_runtime.h>

#define NPTS    65536
#define DIM     128
#define KCODES  1024
#define BM      128      // points per argmin block
#define TILE_C  64       // codes per LDS tile (double-buffered 2x16 KB)
#define NTHR    256      // 4 waves; each wave owns 32 points (ms = 0,1)
#define NTILE   (KCODES / TILE_C)   // 16

typedef _Float16 f16x8 __attribute__((ext_vector_type(8)));
typedef float    f32x4 __attribute__((ext_vector_type(4)));

__device__ __forceinline__ void gload_lds16(const void* g, void* l) {
    __builtin_amdgcn_global_load_lds(
        (const __attribute__((address_space(1))) void*)g,
        (__attribute__((address_space(3))) void*)l, 16, 0, 0);
}

// ---------------- Kernel P: pack codebook -> fp16 frag-order + halfnorm(rounded)
//                  + init acc/ghist/gcursor ------------------------------------
// 64 blocks x 256. g in 0..16383: tc=g>>10 (tile of 64 codes), f=(g>>6)&15,
// l=g&63; f = nt*4+akk ; l = hg*16+n ; code c = tc*64+nt*16+n ; d0 = akk*32+hg*8.
__global__ __launch_bounds__(256)
void pack_kernel(const float* __restrict__ embed, _Float16* __restrict__ ebf,
                 int* __restrict__ ghist, int* __restrict__ gcursor,
                 const float* __restrict__ ema_embed, float* __restrict__ acc,
                 float* __restrict__ hn)
{
    __shared__ float partial[256];
    const int t = threadIdx.x;
    const int b = blockIdx.x;
    const int g = b * 256 + t;                       // 0..16383
    if (g < KCODES) { ghist[g] = 0; gcursor[g] = 0; }
    {   // init acc = 0.8 * ema_embed (2 float4s per thread = 32768 total)
        float4 e0 = reinterpret_cast<const float4*>(ema_embed)[g];
        float4 e1 = reinterpret_cast<const float4*>(ema_embed)[g + 16384];
        reinterpret_cast<float4*>(acc)[g] =
            (float4){0.8f * e0.x, 0.8f * e0.y, 0.8f * e0.z, 0.8f * e0.w};
        reinterpret_cast<float4*>(acc)[g + 16384] =
            (float4){0.8f * e1.x, 0.8f * e1.y, 0.8f * e1.z, 0.8f * e1.w};
    }

    const int tc  = g >> 10;
    const int f   = (g >> 6) & 15;
    const int l   = g & 63;
    const int nt  = f >> 2;
    const int akk = f & 3;
    const int hg  = l >> 4;
    const int n   = l & 15;
    const int c   = tc * TILE_C + nt * 16 + n;
    const int d0  = akk * 32 + hg * 8;
    const float* src = embed + (long)c * DIM + d0;
    float4 v0 = *reinterpret_cast<const float4*>(src);
    float4 v1 = *reinterpret_cast<const float4*>(src + 4);
    float vv[8] = {v0.x, v0.y, v0.z, v0.w, v1.x, v1.y, v1.z, v1.w};
    f16x8 out;
    float ss = 0.f;
    #pragma unroll
    for (int j = 0; j < 8; ++j) {
        _Float16 h = (_Float16)vv[j];                // RNE
        out[j] = h;
        float r = (float)h;                          // halfnorm from ROUNDED values
        ss += r * r;
    }
    *reinterpret_cast<f16x8*>(ebf + (long)g * 8) = out;

    // block b holds 16 complete code rows (tc=b>>2, nt=b&3)
    partial[t] = ss;
    __syncthreads();
    if (t < 16) {
        float s = 0.f;
        #pragma unroll
        for (int k = 0; k < 16; ++k) s += partial[t + k * 16];
        hn[(b >> 2) * TILE_C + (b & 3) * 16 + t] = 0.5f * s;
    }
}

// ---------------- Kernel 1: MFMA fp16 argmin over FULL codebook ----------------
// grid 512. Fused: ind + quantize + histogram (no merge kernel, no kmax).
__global__ __launch_bounds__(NTHR, 2)
void argmin_kernel(const float* __restrict__ x, const _Float16* __restrict__ ebf,
                   const float* __restrict__ halfnorm, const float* __restrict__ embed,
                   int* __restrict__ ind, float* __restrict__ quant,
                   int* __restrict__ ghist)
{
    __shared__ _Float16 es[2][8192];    // 2 x 16 KB double-buffered tile
    __shared__ int      hist[KCODES];   // 4 KB
    __shared__ int      bidx[BM];

    const int t    = threadIdx.x;
    const int lane = t & 63;
    const int w    = t >> 6;           // wave 0..3, owns 32 points
    const int r16  = lane & 15;
    const int h4   = lane >> 4;
    const long xbase = (long)blockIdx.x * BM * DIM;
    const int  wp    = w * 32;

    for (int i = t; i < KCODES; i += NTHR) hist[i] = 0;

    // ---- A fragments: rows (wp + ms*16 + r16), fp16 ----
    f16x8 a[2][4];
    #pragma unroll
    for (int ms = 0; ms < 2; ++ms) {
        const long prow = xbase + (long)(wp + ms * 16 + r16) * DIM;
        #pragma unroll
        for (int akk = 0; akk < 4; ++akk) {
            const float* s = x + prow + akk * 32 + h4 * 8;
            float4 u0 = *reinterpret_cast<const float4*>(s);
            float4 u1 = *reinterpret_cast<const float4*>(s + 4);
            float vv[8] = {u0.x, u0.y, u0.z, u0.w, u1.x, u1.y, u1.z, u1.w};
            #pragma unroll
            for (int j = 0; j < 8; ++j) a[ms][akk][j] = (_Float16)vv[j];
        }
    }

    // ---- prologue: stage tile 0 (wave w loads frags w*4..w*4+3, 1 KB each) ----
    #pragma unroll
    for (int i = 0; i < 4; ++i) {
        const int f = w * 4 + i;
        gload_lds16(ebf + (long)f * 512 + lane * 8, &es[0][f * 512]);
    }
    float hnv_cur[4], hnv_nxt[4];
    #pragma unroll
    for (int nt = 0; nt < 4; ++nt) hnv_cur[nt] = halfnorm[nt * 16 + r16];
    __syncthreads();   // tile 0 resident; hist zeroed

    float bestv[8];
    int   besti[8];
    #pragma unroll
    for (int s = 0; s < 8; ++s) { bestv[s] = -1e30f; besti[s] = 0; }

    #pragma unroll 1
    for (int tile = 0; tile < NTILE; ++tile) {
        // issue next tile's stage + next halfnorms (latency hides under MFMA)
        if (tile + 1 < NTILE) {
            const long gbase = (long)(tile + 1) * 8192;
            #pragma unroll
            for (int i = 0; i < 4; ++i) {
                const int f = w * 4 + i;
                gload_lds16(ebf + gbase + f * 512 + lane * 8, &es[(tile + 1) & 1][f * 512]);
            }
            #pragma unroll
            for (int nt = 0; nt < 4; ++nt)
                hnv_nxt[nt] = halfnorm[(tile + 1) * TILE_C + nt * 16 + r16];
        }

        f32x4 C[4][2];
        #pragma unroll
        for (int nt = 0; nt < 4; ++nt)
            #pragma unroll
            for (int ms = 0; ms < 2; ++ms) C[nt][ms] = (f32x4){0.f, 0.f, 0.f, 0.f};

        #pragma unroll
        for (int akk = 0; akk < 4; ++akk) {
            #pragma unroll
            for (int nt = 0; nt < 4; ++nt) {
                f16x8 B = *reinterpret_cast<const f16x8*>(
                    &es[tile & 1][(nt * 4 + akk) * 512 + lane * 8]);
                C[nt][0] = __builtin_amdgcn_mfma_f32_16x16x32_f16(a[0][akk], B, C[nt][0], 0, 0, 0);
                C[nt][1] = __builtin_amdgcn_mfma_f32_16x16x32_f16(a[1][akk], B, C[nt][1], 0, 0, 0);
            }
        }

        // ---- scores + running argmax (codes ascending: tile asc, nt asc) ----
        #pragma unroll
        for (int nt = 0; nt < 4; ++nt) {
            const int c = tile * TILE_C + nt * 16 + r16;
            #pragma unroll
            for (int ms = 0; ms < 2; ++ms)
                #pragma unroll
                for (int reg = 0; reg < 4; ++reg) {
                    float sc  = C[nt][ms][reg] - hnv_cur[nt];
                    int  slot = ms * 4 + reg;
                    if (sc > bestv[slot]) { bestv[slot] = sc; besti[slot] = c; }
                }
        }
        #pragma unroll
        for (int nt = 0; nt < 4; ++nt) hnv_cur[nt] = hnv_nxt[nt];
        __syncthreads();   // next tile resident; current tile readers done
    }

    // ---- butterfly reduce across 16 columns, tie -> smaller idx ----
    #pragma unroll
    for (int s = 0; s < 8; ++s) {
        float v = bestv[s];
        int   i = besti[s];
        #pragma unroll
        for (int off = 1; off < 16; off <<= 1) {
            float ov = __shfl_xor(v, off);
            int   oi = __shfl_xor(i, off);
            if (ov > v || (ov == v && oi < i)) { v = ov; i = oi; }
        }
        bestv[s] = v; besti[s] = i;
    }
    if (r16 == 0) {
        #pragma unroll
        for (int s = 0; s < 8; ++s) {
            int ms = s >> 2, reg = s & 3;
            int p  = wp + ms * 16 + h4 * 4 + reg;
            bidx[p] = besti[s];
            ind[blockIdx.x * BM + p] = besti[s];
        }
    }
    __syncthreads();

    // ---- LDS histogram of this block's 128 assignments ----
    if (t < BM) atomicAdd(&hist[bidx[t]], 1);

    // ---- quantize: lane-contiguous gather-copy of embed[best] ----
    float4* dst = reinterpret_cast<float4*>(quant + xbase);
    #pragma unroll
    for (int i = 0; i < 16; ++i) {
        int idx = i * NTHR + t;          // 0..4095
        int p   = idx >> 5;
        int q   = idx & 31;
        int c   = bidx[p];
        dst[idx] = reinterpret_cast<const float4*>(embed + (long)c * DIM)[q];
    }

    __syncthreads();
    for (int i = t; i < KCODES; i += NTHR)
        if (hist[i]) atomicAdd(&ghist[i], hist[i]);
}

// ---------------- Kernel C: scan(ghist) in-block + scatter + ema_num_new -------
__global__ __launch_bounds__(256)
void scatter_kernel(const int* __restrict__ ghist, const int* __restrict__ ind,
                    const float* __restrict__ ema_num, float* __restrict__ ema_num_new,
                    int* __restrict__ gcursor, int* __restrict__ sorted,
                    int* __restrict__ scode)
{
    __shared__ int off_lds[KCODES];
    __shared__ int wsum[4];
    const int t    = threadIdx.x;
    const int lane = t & 63;
    const int w    = t >> 6;

    int v[4], pre[4];
    int s = 0;
    #pragma unroll
    for (int j = 0; j < 4; ++j) {
        v[j] = ghist[t * 4 + j];
        pre[j] = s;
        s += v[j];
    }
    int incl = s;
    #pragma unroll
    for (int off = 1; off < 64; off <<= 1) {
        int u = __shfl_up(incl, off);
        if (lane >= off) incl += u;
    }
    if (lane == 63) wsum[w] = incl;
    __syncthreads();
    if (t == 0) {
        int a = 0;
        #pragma unroll
        for (int k = 0; k < 4; ++k) { int tmp = wsum[k]; wsum[k] = a; a += tmp; }
    }
    __syncthreads();
    const int excl = wsum[w] + incl - s;
    #pragma unroll
    for (int j = 0; j < 4; ++j) off_lds[t * 4 + j] = excl + pre[j];

    if (blockIdx.x == 0) {
        #pragma unroll
        for (int j = 0; j < 4; ++j)
            ema_num_new[t * 4 + j] = ema_num[t * 4 + j] * 0.8f + 0.2f * (float)v[j];
    }
    __syncthreads();

    const int p = blockIdx.x * 256 + t;
    const int c = ind[p];
    const int pos = off_lds[c] + atomicAdd(&gcursor[c], 1);
    sorted[pos] = p;
    scode[pos]  = c;
}

// ---------------- Kernel G: chunked run-sum over sorted order ------------------
__global__ __launch_bounds__(128)
void sum2_kernel(const float* __restrict__ x, const int* __restrict__ sorted,
                 const int* __restrict__ scode, float* __restrict__ acc)
{
    __shared__ int sp[64];
    __shared__ int sc[64];
    const int t = threadIdx.x;
    const int base = blockIdx.x * 64;
    if (t < 64) { sp[t] = sorted[base + t]; sc[t] = scode[base + t]; }
    __syncthreads();

    float a = 0.f;
    int cprev = sc[0];
    #pragma unroll 1
    for (int kk = 0; kk < 8; ++kk) {
        float v[8];
        #pragma unroll
        for (int i = 0; i < 8; ++i)
            v[i] = x[(long)sp[kk * 8 + i] * DIM + t];      // 8 independent 512B rows
        #pragma unroll
        for (int i = 0; i < 8; ++i) {
            const int c = sc[kk * 8 + i];                  // wave-uniform
            if (c != cprev) {
                atomicAdd(&acc[(long)cprev * DIM + t], 0.2f * a);
                a = 0.f; cprev = c;
            }
            a += v[i];
        }
    }
    atomicAdd(&acc[(long)cprev * DIM + t], 0.2f * a);
}

// ---------------- Kernel F: embed_new = ema_embed_new / ema_num_new ------------
__global__ __launch_bounds__(256)
void final_kernel(const float* __restrict__ acc, const float* __restrict__ ema_num_new,
                  float* __restrict__ embed_new)
{
    const int g = blockIdx.x * 256 + threadIdx.x;   // 0..32767 float4s
    float4 v = reinterpret_cast<const float4*>(acc)[g];
    const float en = ema_num_new[g >> 5];           // 32 float4s per code row
    float4 o = {v.x / en, v.y / en, v.z / en, v.w / en};
    reinterpret_cast<float4*>(embed_new)[g] = o;
}

extern "C" void kernel_launch(void* const* d_in, const int* in_sizes, int n_in,
                              void* d_out, int out_size, void* d_ws, size_t ws_size,
                              hipStream_t stream)
{
    const float* x         = (const float*)d_in[0];
    const float* embed     = (const float*)d_in[1];
    const float* ema_embed = (const float*)d_in[2];
    const float* ema_num   = (const float*)d_in[3];

    float* out0 = (float*)d_out;            // quantize      (16*4096*128)
    float* out1 = out0 + 8388608;           // embed_new     (1024*128)
    float* out2 = out1 + 131072;            // ema_embed_new (1024*128)
    float* out3 = out2 + 131072;            // ema_num_new   (1024)

    char* ws = (char*)d_ws;
    float*    hn      = (float*)ws;                 // 4 KB
    int*      ind     = (int*)(ws + 4096);          // 256 KB
    _Float16* ebf     = (_Float16*)(ws + 266240);   // 256 KB
    int*      ghist   = (int*)(ws + 528384);        // 4 KB
    int*      gcursor = (int*)(ws + 532480);        // 4 KB
    int*      sorted  = (int*)(ws + 536576);        // 256 KB
    int*      scode   = (int*)(ws + 798720);        // 256 KB

    pack_kernel<<<64, 256, 0, stream>>>(embed, ebf, ghist, gcursor, ema_embed,
                                        out2, hn);
    argmin_kernel<<<NPTS / BM, NTHR, 0, stream>>>(x, ebf, hn, embed, ind, out0, ghist);
    scatter_kernel<<<NPTS / 256, 256, 0, stream>>>(ghist, ind, ema_num, out3,
                                                   gcursor, sorted, scode);
    sum2_kernel<<<NPTS / 64, 128, 0, stream>>>(x, sorted, scode, out2);
    final_kernel<<<128, 256, 0, stream>>>(out2, out3, out1);
}

// Round 16
// 95.962 us; speedup vs baseline: 1.5987x; 1.0018x over previous
//
#include <hip/hip_runtime.h>

#define NPTS    65536
#define DIM     128
#define KCODES  1024
#define BM      64       // points per argmin block (grid 1024 -> 4 blocks/CU)
#define TILE_C  64       // codes per LDS tile (double-buffered 2x16 KB)
#define NTHR    256      // 4 waves; each wave owns 16 points
#define NTILE   (KCODES / TILE_C)   // 16

typedef _Float16 f16x8 __attribute__((ext_vector_type(8)));
typedef float    f32x4 __attribute__((ext_vector_type(4)));

__device__ __forceinline__ void gload_lds16(const void* g, void* l) {
    __builtin_amdgcn_global_load_lds(
        (const __attribute__((address_space(1))) void*)g,
        (__attribute__((address_space(3))) void*)l, 16, 0, 0);
}

// ---------------- Kernel P: pack codebook -> fp16 frag-order + halfnorm(rounded)
//                  + init acc/ghist/gcursor ------------------------------------
// 64 blocks x 256. g in 0..16383: tc=g>>10 (tile of 64 codes), f=(g>>6)&15,
// l=g&63; f = nt*4+akk ; l = hg*16+n ; code c = tc*64+nt*16+n ; d0 = akk*32+hg*8.
__global__ __launch_bounds__(256)
void pack_kernel(const float* __restrict__ embed, _Float16* __restrict__ ebf,
                 int* __restrict__ ghist, int* __restrict__ gcursor,
                 const float* __restrict__ ema_embed, float* __restrict__ acc,
                 float* __restrict__ hn)
{
    __shared__ float partial[256];
    const int t = threadIdx.x;
    const int b = blockIdx.x;
    const int g = b * 256 + t;                       // 0..16383
    if (g < KCODES) { ghist[g] = 0; gcursor[g] = 0; }
    {   // init acc = 0.8 * ema_embed (2 float4s per thread = 32768 total)
        float4 e0 = reinterpret_cast<const float4*>(ema_embed)[g];
        float4 e1 = reinterpret_cast<const float4*>(ema_embed)[g + 16384];
        reinterpret_cast<float4*>(acc)[g] =
            (float4){0.8f * e0.x, 0.8f * e0.y, 0.8f * e0.z, 0.8f * e0.w};
        reinterpret_cast<float4*>(acc)[g + 16384] =
            (float4){0.8f * e1.x, 0.8f * e1.y, 0.8f * e1.z, 0.8f * e1.w};
    }

    const int tc  = g >> 10;
    const int f   = (g >> 6) & 15;
    const int l   = g & 63;
    const int nt  = f >> 2;
    const int akk = f & 3;
    const int hg  = l >> 4;
    const int n   = l & 15;
    const int c   = tc * TILE_C + nt * 16 + n;
    const int d0  = akk * 32 + hg * 8;
    const float* src = embed + (long)c * DIM + d0;
    float4 v0 = *reinterpret_cast<const float4*>(src);
    float4 v1 = *reinterpret_cast<const float4*>(src + 4);
    float vv[8] = {v0.x, v0.y, v0.z, v0.w, v1.x, v1.y, v1.z, v1.w};
    f16x8 out;
    float ss = 0.f;
    #pragma unroll
    for (int j = 0; j < 8; ++j) {
        _Float16 h = (_Float16)vv[j];                // RNE
        out[j] = h;
        float r = (float)h;                          // halfnorm from ROUNDED values
        ss += r * r;
    }
    *reinterpret_cast<f16x8*>(ebf + (long)g * 8) = out;

    // block b holds 16 complete code rows (tc=b>>2, nt=b&3)
    partial[t] = ss;
    __syncthreads();
    if (t < 16) {
        float s = 0.f;
        #pragma unroll
        for (int k = 0; k < 16; ++k) s += partial[t + k * 16];
        hn[(b >> 2) * TILE_C + (b & 3) * 16 + t] = 0.5f * s;
    }
}

// ---------------- Kernel 1: MFMA fp16 argmin over FULL codebook ----------------
// grid 1024 (BM=64). Fused: ind + quantize + histogram.
__global__ __launch_bounds__(NTHR, 4)
void argmin_kernel(const float* __restrict__ x, const _Float16* __restrict__ ebf,
                   const float* __restrict__ halfnorm, const float* __restrict__ embed,
                   int* __restrict__ ind, float* __restrict__ quant,
                   int* __restrict__ ghist)
{
    __shared__ _Float16 es[2][8192];    // 2 x 16 KB double-buffered tile
    __shared__ int      hist[KCODES];   // 4 KB
    __shared__ int      bidx[BM];

    const int t    = threadIdx.x;
    const int lane = t & 63;
    const int w    = t >> 6;           // wave 0..3, owns 16 points
    const int r16  = lane & 15;
    const int h4   = lane >> 4;
    const long xbase = (long)blockIdx.x * BM * DIM;
    const int  wp    = w * 16;

    for (int i = t; i < KCODES; i += NTHR) hist[i] = 0;

    // ---- A fragments: row (wp + r16), fp16 ----
    f16x8 a[4];
    {
        const long prow = xbase + (long)(wp + r16) * DIM;
        #pragma unroll
        for (int akk = 0; akk < 4; ++akk) {
            const float* s = x + prow + akk * 32 + h4 * 8;
            float4 u0 = *reinterpret_cast<const float4*>(s);
            float4 u1 = *reinterpret_cast<const float4*>(s + 4);
            float vv[8] = {u0.x, u0.y, u0.z, u0.w, u1.x, u1.y, u1.z, u1.w};
            #pragma unroll
            for (int j = 0; j < 8; ++j) a[akk][j] = (_Float16)vv[j];
        }
    }

    // ---- prologue: stage tile 0 (wave w loads frags w*4..w*4+3, 1 KB each) ----
    #pragma unroll
    for (int i = 0; i < 4; ++i) {
        const int f = w * 4 + i;
        gload_lds16(ebf + (long)f * 512 + lane * 8, &es[0][f * 512]);
    }
    float hnv_cur[4], hnv_nxt[4];
    #pragma unroll
    for (int nt = 0; nt < 4; ++nt) hnv_cur[nt] = halfnorm[nt * 16 + r16];
    __syncthreads();   // tile 0 resident; hist zeroed

    float bestv[4];
    int   besti[4];
    #pragma unroll
    for (int s = 0; s < 4; ++s) { bestv[s] = -1e30f; besti[s] = 0; }

    #pragma unroll 1
    for (int tile = 0; tile < NTILE; ++tile) {
        // issue next tile's stage + next halfnorms (latency hides under MFMA)
        if (tile + 1 < NTILE) {
            const long gbase = (long)(tile + 1) * 8192;
            #pragma unroll
            for (int i = 0; i < 4; ++i) {
                const int f = w * 4 + i;
                gload_lds16(ebf + gbase + f * 512 + lane * 8, &es[(tile + 1) & 1][f * 512]);
            }
            #pragma unroll
            for (int nt = 0; nt < 4; ++nt)
                hnv_nxt[nt] = halfnorm[(tile + 1) * TILE_C + nt * 16 + r16];
        }

        f32x4 C[4];
        #pragma unroll
        for (int nt = 0; nt < 4; ++nt) C[nt] = (f32x4){0.f, 0.f, 0.f, 0.f};

        #pragma unroll
        for (int akk = 0; akk < 4; ++akk) {
            #pragma unroll
            for (int nt = 0; nt < 4; ++nt) {
                f16x8 B = *reinterpret_cast<const f16x8*>(
                    &es[tile & 1][(nt * 4 + akk) * 512 + lane * 8]);
                C[nt] = __builtin_amdgcn_mfma_f32_16x16x32_f16(a[akk], B, C[nt], 0, 0, 0);
            }
        }

        // ---- scores + running argmax (codes ascending: tile asc, nt asc) ----
        #pragma unroll
        for (int nt = 0; nt < 4; ++nt) {
            const int c = tile * TILE_C + nt * 16 + r16;
            #pragma unroll
            for (int reg = 0; reg < 4; ++reg) {
                float sc = C[nt][reg] - hnv_cur[nt];
                if (sc > bestv[reg]) { bestv[reg] = sc; besti[reg] = c; }
            }
        }
        #pragma unroll
        for (int nt = 0; nt < 4; ++nt) hnv_cur[nt] = hnv_nxt[nt];
        __syncthreads();   // next tile resident; current tile readers done
    }

    // ---- butterfly reduce across 16 columns, tie -> smaller idx ----
    #pragma unroll
    for (int s = 0; s < 4; ++s) {
        float v = bestv[s];
        int   i = besti[s];
        #pragma unroll
        for (int off = 1; off < 16; off <<= 1) {
            float ov = __shfl_xor(v, off);
            int   oi = __shfl_xor(i, off);
            if (ov > v || (ov == v && oi < i)) { v = ov; i = oi; }
        }
        bestv[s] = v; besti[s] = i;
    }
    if (r16 == 0) {
        #pragma unroll
        for (int s = 0; s < 4; ++s) {
            int p = wp + h4 * 4 + s;     // point = row (h4*4 + reg)
            bidx[p] = besti[s];
            ind[blockIdx.x * BM + p] = besti[s];
        }
    }
    __syncthreads();

    // ---- LDS histogram of this block's 64 assignments ----
    if (t < BM) atomicAdd(&hist[bidx[t]], 1);

    // ---- quantize: lane-contiguous gather-copy of embed[best] ----
    float4* dst = reinterpret_cast<float4*>(quant + xbase);
    #pragma unroll
    for (int i = 0; i < 8; ++i) {
        int idx = i * NTHR + t;          // 0..2047
        int p   = idx >> 5;
        int q   = idx & 31;
        int c   = bidx[p];
        dst[idx] = reinterpret_cast<const float4*>(embed + (long)c * DIM)[q];
    }

    __syncthreads();
    for (int i = t; i < KCODES; i += NTHR)
        if (hist[i]) atomicAdd(&ghist[i], hist[i]);
}

// ---------------- Kernel C: scan(ghist) in-block + scatter + ema_num_new -------
__global__ __launch_bounds__(256)
void scatter_kernel(const int* __restrict__ ghist, const int* __restrict__ ind,
                    const float* __restrict__ ema_num, float* __restrict__ ema_num_new,
                    int* __restrict__ gcursor, int* __restrict__ sorted,
                    int* __restrict__ scode)
{
    __shared__ int off_lds[KCODES];
    __shared__ int wsum[4];
    const int t    = threadIdx.x;
    const int lane = t & 63;
    const int w    = t >> 6;

    int v[4], pre[4];
    int s = 0;
    #pragma unroll
    for (int j = 0; j < 4; ++j) {
        v[j] = ghist[t * 4 + j];
        pre[j] = s;
        s += v[j];
    }
    int incl = s;
    #pragma unroll
    for (int off = 1; off < 64; off <<= 1) {
        int u = __shfl_up(incl, off);
        if (lane >= off) incl += u;
    }
    if (lane == 63) wsum[w] = incl;
    __syncthreads();
    if (t == 0) {
        int a = 0;
        #pragma unroll
        for (int k = 0; k < 4; ++k) { int tmp = wsum[k]; wsum[k] = a; a += tmp; }
    }
    __syncthreads();
    const int excl = wsum[w] + incl - s;
    #pragma unroll
    for (int j = 0; j < 4; ++j) off_lds[t * 4 + j] = excl + pre[j];

    if (blockIdx.x == 0) {
        #pragma unroll
        for (int j = 0; j < 4; ++j)
            ema_num_new[t * 4 + j] = ema_num[t * 4 + j] * 0.8f + 0.2f * (float)v[j];
    }
    __syncthreads();

    const int p = blockIdx.x * 256 + t;
    const int c = ind[p];
    const int pos = off_lds[c] + atomicAdd(&gcursor[c], 1);
    sorted[pos] = p;
    scode[pos]  = c;
}

// ---------------- Kernel G: chunked run-sum over sorted order ------------------
__global__ __launch_bounds__(128)
void sum2_kernel(const float* __restrict__ x, const int* __restrict__ sorted,
                 const int* __restrict__ scode, float* __restrict__ acc)
{
    __shared__ int sp[64];
    __shared__ int sc[64];
    const int t = threadIdx.x;
    const int base = blockIdx.x * 64;
    if (t < 64) { sp[t] = sorted[base + t]; sc[t] = scode[base + t]; }
    __syncthreads();

    float a = 0.f;
    int cprev = sc[0];
    #pragma unroll 1
    for (int kk = 0; kk < 8; ++kk) {
        float v[8];
        #pragma unroll
        for (int i = 0; i < 8; ++i)
            v[i] = x[(long)sp[kk * 8 + i] * DIM + t];      // 8 independent 512B rows
        #pragma unroll
        for (int i = 0; i < 8; ++i) {
            const int c = sc[kk * 8 + i];                  // wave-uniform
            if (c != cprev) {
                atomicAdd(&acc[(long)cprev * DIM + t], 0.2f * a);
                a = 0.f; cprev = c;
            }
            a += v[i];
        }
    }
    atomicAdd(&acc[(long)cprev * DIM + t], 0.2f * a);
}

// ---------------- Kernel F: embed_new = ema_embed_new / ema_num_new ------------
__global__ __launch_bounds__(256)
void final_kernel(const float* __restrict__ acc, const float* __restrict__ ema_num_new,
                  float* __restrict__ embed_new)
{
    const int g = blockIdx.x * 256 + threadIdx.x;   // 0..32767 float4s
    float4 v = reinterpret_cast<const float4*>(acc)[g];
    const float en = ema_num_new[g >> 5];           // 32 float4s per code row
    float4 o = {v.x / en, v.y / en, v.z / en, v.w / en};
    reinterpret_cast<float4*>(embed_new)[g] = o;
}

extern "C" void kernel_launch(void* const* d_in, const int* in_sizes, int n_in,
                              void* d_out, int out_size, void* d_ws, size_t ws_size,
                              hipStream_t stream)
{
    const float* x         = (const float*)d_in[0];
    const float* embed     = (const float*)d_in[1];
    const float* ema_embed = (const float*)d_in[2];
    const float* ema_num   = (const float*)d_in[3];

    float* out0 = (float*)d_out;            // quantize      (16*4096*128)
    float* out1 = out0 + 8388608;           // embed_new     (1024*128)
    float* out2 = out1 + 131072;            // ema_embed_new (1024*128)
    float* out3 = out2 + 131072;            // ema_num_new   (1024)

    char* ws = (char*)d_ws;
    float*    hn      = (float*)ws;                 // 4 KB
    int*      ind     = (int*)(ws + 4096);          // 256 KB
    _Float16* ebf     = (_Float16*)(ws + 266240);   // 256 KB
    int*      ghist   = (int*)(ws + 528384);        // 4 KB
    int*      gcursor = (int*)(ws + 532480);        // 4 KB
    int*      sorted  = (int*)(ws + 536576);        // 256 KB
    int*      scode   = (int*)(ws + 798720);        // 256 KB

    pack_kernel<<<64, 256, 0, stream>>>(embed, ebf, ghist, gcursor, ema_embed,
                                        out2, hn);
    argmin_kernel<<<NPTS / BM, NTHR, 0, stream>>>(x, ebf, hn, embed, ind, out0, ghist);
    scatter_kernel<<<NPTS / 256, 256, 0, stream>>>(ghist, ind, ema_num, out3,
                                                   gcursor, sorted, scode);
    sum2_kernel<<<NPTS / 64, 128, 0, stream>>>(x, sorted, scode, out2);
    final_kernel<<<128, 256, 0, stream>>>(out2, out3, out1);
}